// Round 1
// baseline (260.331 us; speedup 1.0000x reference)
//
#include <hip/hip_runtime.h>
#include <math.h>

#define Bn 128
#define Ln 256
#define Hn 1024
#define Tn 9

__device__ __forceinline__ float dot4(float4 a, float4 b) {
  return a.x*b.x + a.y*b.y + a.z*b.z + a.w*b.w;
}

// ---------------------------------------------------------------------------
// K1: emissions[row][t] = dot(hidden[row,:], W[t,:]) + b[t]
// wave-per-row; W cached in registers (36 float4/lane); coalesced float4 loads.
// ---------------------------------------------------------------------------
__global__ __launch_bounds__(256, 2) void emis_kernel(
    const float* __restrict__ hidden, const float* __restrict__ W,
    const float* __restrict__ bias, float* __restrict__ em)
{
  const int lane = threadIdx.x & 63;
  const int wid  = blockIdx.x * (blockDim.x >> 6) + (threadIdx.x >> 6);
  const int nw   = gridDim.x * (blockDim.x >> 6);

  // W[t][h]: lane's slice h = lane*4 + j*256  (float4 index t*256 + j*64 + lane)
  const float4* W4 = (const float4*)W;
  float4 w[9][4];
#pragma unroll
  for (int t = 0; t < 9; ++t)
#pragma unroll
    for (int j = 0; j < 4; ++j)
      w[t][j] = W4[t*256 + j*64 + lane];

  const int NROWS = Bn * Ln;
  int row = wid;
  if (row >= NROWS) return;

  const float4* hp = (const float4*)hidden + (size_t)row * 256 + lane;
  float4 h0 = hp[0], h1 = hp[64], h2 = hp[128], h3 = hp[192];

  while (true) {
    const int nrow = row + nw;
    float4 n0, n1, n2, n3;
    if (nrow < NROWS) {  // prefetch next row while computing this one
      const float4* hq = (const float4*)hidden + (size_t)nrow * 256 + lane;
      n0 = hq[0]; n1 = hq[64]; n2 = hq[128]; n3 = hq[192];
    }

    float acc[9];
#pragma unroll
    for (int t = 0; t < 9; ++t)
      acc[t] = dot4(h0, w[t][0]) + dot4(h1, w[t][1])
             + dot4(h2, w[t][2]) + dot4(h3, w[t][3]);

    // full-wave butterfly sum for each of the 9 tags
#pragma unroll
    for (int t = 0; t < 9; ++t) {
#pragma unroll
      for (int m = 1; m < 64; m <<= 1)
        acc[t] += __shfl_xor(acc[t], m, 64);
    }

    // lane k (k<9) writes tag k  (compile-time register indices only)
    float v = acc[0];
#pragma unroll
    for (int t = 1; t < 9; ++t)
      if (lane == t) v = acc[t];
    if (lane < 9) em[(size_t)row * 9 + lane] = v + bias[lane];

    if (nrow >= NROWS) break;
    row = nrow; h0 = n0; h1 = n1; h2 = n2; h3 = n3;
  }
}

// ---------------------------------------------------------------------------
// K2: per-batch CRF numerator + forward-algorithm denominator.
// One wave per batch element. Lanes 0..8 carry forward scores.
// ---------------------------------------------------------------------------
__global__ __launch_bounds__(64) void crf_kernel(
    const float* __restrict__ em, const int* __restrict__ labels,
    const int* __restrict__ lengths, const float* __restrict__ start_t,
    const float* __restrict__ end_t, const float* __restrict__ trans,
    float* __restrict__ llh)
{
  const int b    = blockIdx.x;
  const int lane = threadIdx.x;
  const int len  = lengths[b];                // in [1, Ln]
  const float* emb = em + (size_t)b * Ln * Tn;
  const int*   tg  = labels + b * Ln;

  // ---- numerator: gold-path score, lane-strided over timesteps ----
  float part = 0.f;
  for (int t = lane; t < len; t += 64) {
    const int cur = tg[t];
    float v;
    if (t == 0) v = start_t[cur] + emb[cur];
    else        v = trans[tg[t-1] * Tn + cur] + emb[t * Tn + cur];
    if (t == len - 1) v += end_t[cur];
    part += v;
  }
#pragma unroll
  for (int m = 1; m < 64; m <<= 1) part += __shfl_xor(part, m, 64);
  const float num = part;

  // ---- denominator: forward recursion, lane j = next-state ----
  const int j = (lane < Tn) ? lane : 0;
  float trc[9];
#pragma unroll
  for (int i = 0; i < 9; ++i) trc[i] = trans[i * Tn + j];   // column j

  float score = start_t[j] + emb[j];
  for (int t = 1; t < len; ++t) {
    const float e = emb[t * Tn + j];
    float a[9];
#pragma unroll
    for (int i = 0; i < 9; ++i) a[i] = __shfl(score, i, 64) + trc[i];
    float mx = a[0];
#pragma unroll
    for (int i = 1; i < 9; ++i) mx = fmaxf(mx, a[i]);
    float s = 0.f;
#pragma unroll
    for (int i = 0; i < 9; ++i) s += __expf(a[i] - mx);
    score = mx + __logf(s) + e;
  }

  // denom = logsumexp_j(score_j + end_t[j]) over lanes 0..8
  float fin = (lane < Tn) ? (score + end_t[j]) : -1.0e30f;
  float mx = fin;
#pragma unroll
  for (int m = 1; m < 64; m <<= 1) mx = fmaxf(mx, __shfl_xor(mx, m, 64));
  float se = __expf(fin - mx);
#pragma unroll
  for (int m = 1; m < 64; m <<= 1) se += __shfl_xor(se, m, 64);
  const float denom = mx + __logf(se);

  if (lane == 0) llh[b] = num - denom;
}

// ---------------------------------------------------------------------------
// K3: out = -mean(llh)
// ---------------------------------------------------------------------------
__global__ __launch_bounds__(64) void reduce_kernel(
    const float* __restrict__ llh, float* __restrict__ out)
{
  const int lane = threadIdx.x;
  float v = llh[lane] + llh[lane + 64];
#pragma unroll
  for (int m = 1; m < 64; m <<= 1) v += __shfl_xor(v, m, 64);
  if (lane == 0) out[0] = -v * (1.0f / Bn);
}

extern "C" void kernel_launch(void* const* d_in, const int* in_sizes, int n_in,
                              void* d_out, int out_size, void* d_ws, size_t ws_size,
                              hipStream_t stream) {
  const float* hidden  = (const float*)d_in[0];
  const float* W       = (const float*)d_in[1];
  const float* bias    = (const float*)d_in[2];
  const float* start_t = (const float*)d_in[3];
  const float* end_t   = (const float*)d_in[4];
  const float* trans   = (const float*)d_in[5];
  const int*   labels  = (const int*)d_in[6];
  const int*   lengths = (const int*)d_in[7];

  float* out = (float*)d_out;
  float* em  = (float*)d_ws;                       // 32768*9 floats = 1.18 MB
  float* llh = em + (size_t)Bn * Ln * Tn;          // +128 floats

  emis_kernel<<<512, 256, 0, stream>>>(hidden, W, bias, em);
  crf_kernel<<<Bn, 64, 0, stream>>>(em, labels, lengths, start_t, end_t, trans, llh);
  reduce_kernel<<<1, 64, 0, stream>>>(llh, out);
}

// Round 2
// 246.262 us; speedup vs baseline: 1.0571x; 1.0571x over previous
//
#include <hip/hip_runtime.h>
#include <math.h>

#define Bn 128
#define Ln 256
#define Hn 1024
#define Tn 9
#define NROWS (Bn * Ln)          // 32768
#define NTILE (NROWS / 16)       // 2048
#define EMN   (NROWS * Tn)       // 294912

typedef short short8 __attribute__((ext_vector_type(8)));
typedef float f32x4  __attribute__((ext_vector_type(4)));
typedef int   i32x4  __attribute__((ext_vector_type(4)));

__device__ __forceinline__ unsigned cvt_pk_bf16(float a, float b) {
  unsigned r;
  asm("v_cvt_pk_bf16_f32 %0, %1, %2" : "=v"(r) : "v"(a), "v"(b));
  return r;
}

__device__ __forceinline__ short8 pack_bf16x8(float4 lo, float4 hi) {
  i32x4 u;
  u[0] = cvt_pk_bf16(lo.x, lo.y);
  u[1] = cvt_pk_bf16(lo.z, lo.w);
  u[2] = cvt_pk_bf16(hi.x, hi.y);
  u[3] = cvt_pk_bf16(hi.z, hi.w);
  return __builtin_bit_cast(short8, u);
}

// ---------------------------------------------------------------------------
// K1: emissions GEMM via bf16 MFMA, K-split 4.
// Task = (tile of 16 rows, k-split s of 256). Wave per task.
// A-frag: row = lane&15, k = 8*(lane>>4)+j (contiguous 8 floats -> cvt_pk).
// B-frag: col(tag) = lane&15, same k slice of W[tag][:]. cols 9..15 zero.
// C/D: col = lane&15, row = 4*(lane>>4)+reg.
// ---------------------------------------------------------------------------
__global__ __launch_bounds__(256, 4) void emis_mfma_kernel(
    const float* __restrict__ hidden, const float* __restrict__ W,
    float* __restrict__ part)
{
  const int lane = threadIdx.x & 63;
  const int wid  = blockIdx.x * 4 + (threadIdx.x >> 6);   // 0..8191
  const int s    = wid & 3;                               // k-split
  const int tile = wid >> 2;                              // 0..2047
  const int col  = lane & 15;
  const int g    = lane >> 4;

  // B fragments for this k-split: 8 MFMAs x 8 bf16
  short8 bfrag[8];
  if (col < Tn) {
    const float* wr = W + col * Hn + s * 256 + g * 8;
#pragma unroll
    for (int m = 0; m < 8; ++m) {
      float4 lo = *(const float4*)(wr + m * 32);
      float4 hi = *(const float4*)(wr + m * 32 + 4);
      bfrag[m] = pack_bf16x8(lo, hi);
    }
  } else {
#pragma unroll
    for (int m = 0; m < 8; ++m) bfrag[m] = (short8)0;
  }

  // batch-issue all 16 A loads (256B/lane in flight), then cvt+mfma
  const float* A = hidden + (size_t)tile * 16 * Hn + (size_t)col * Hn + s * 256 + g * 8;
  float4 lo[8], hi[8];
#pragma unroll
  for (int m = 0; m < 8; ++m) {
    lo[m] = *(const float4*)(A + m * 32);
    hi[m] = *(const float4*)(A + m * 32 + 4);
  }
  f32x4 acc = {0.f, 0.f, 0.f, 0.f};
#pragma unroll
  for (int m = 0; m < 8; ++m) {
    short8 af = pack_bf16x8(lo[m], hi[m]);
    acc = __builtin_amdgcn_mfma_f32_16x16x32_bf16(af, bfrag[m], acc, 0, 0, 0);
  }

  if (col < Tn) {
    float* p = part + (size_t)s * EMN;
    const int rbase = tile * 16 + g * 4;
#pragma unroll
    for (int r = 0; r < 4; ++r)
      p[(size_t)(rbase + r) * Tn + col] = acc[r];
  }
}

// ---------------------------------------------------------------------------
// K2: em = sum of 4 partials + bias
// ---------------------------------------------------------------------------
__global__ __launch_bounds__(256) void combine_kernel(
    const float* __restrict__ part, const float* __restrict__ bias,
    float* __restrict__ em)
{
  const int i = blockIdx.x * 256 + threadIdx.x;   // < EMN (grid sized exactly)
  float v = part[i] + part[i + EMN] + part[i + 2 * EMN] + part[i + 3 * EMN];
  em[i] = v + bias[i % Tn];
}

// ---------------------------------------------------------------------------
// K3: chunk transfer matrices. Block = one (b, chunk c, start-state s0) wave.
// Chunk c covers steps t in [max(1,32c), min(32c+32, len)); identity if empty.
// M[b][c][s0][j] = log-semiring matrix entry.
// ---------------------------------------------------------------------------
__global__ __launch_bounds__(64) void crfA_kernel(
    const float* __restrict__ em, const int* __restrict__ lengths,
    const float* __restrict__ trans, float* __restrict__ M)
{
  const int bid = blockIdx.x;                    // Bn*8*9
  const int b = bid / 72, rem = bid % 72, c = rem / 9, s0 = rem % 9;
  const int lane = threadIdx.x;
  const int j = (lane < Tn) ? lane : 0;
  const int len = lengths[b];
  int lo = c * 32; if (lo < 1) lo = 1;
  int hi = c * 32 + 32; if (hi > len) hi = len;

  float trc[9];
#pragma unroll
  for (int i = 0; i < 9; ++i) trc[i] = trans[i * Tn + j];

  float score = (j == s0) ? 0.f : -1.0e30f;
  const float* emb = em + (size_t)b * Ln * Tn;
  for (int t = lo; t < hi; ++t) {
    const float e = emb[t * Tn + j];             // independent of chain: prefetchable
    float a[9];
#pragma unroll
    for (int i = 0; i < 9; ++i) a[i] = __shfl(score, i, 64) + trc[i];
    float mx = a[0];
#pragma unroll
    for (int i = 1; i < 9; ++i) mx = fmaxf(mx, a[i]);
    float ssum = 0.f;
#pragma unroll
    for (int i = 0; i < 9; ++i) ssum += __expf(a[i] - mx);
    score = mx + __logf(ssum) + e;
  }
  if (lane < Tn)
    M[((size_t)(b * 8 + c) * 9 + s0) * 9 + lane] = score;
}

// ---------------------------------------------------------------------------
// K4: per-batch compose 8 chunk matrices + numerator -> llh[b]
// ---------------------------------------------------------------------------
__global__ __launch_bounds__(64) void crfB_kernel(
    const float* __restrict__ em, const int* __restrict__ labels,
    const int* __restrict__ lengths, const float* __restrict__ start_t,
    const float* __restrict__ end_t, const float* __restrict__ trans,
    const float* __restrict__ M, float* __restrict__ llh)
{
  const int b = blockIdx.x, lane = threadIdx.x;
  const int len = lengths[b];
  const float* emb = em + (size_t)b * Ln * Tn;
  const int* tg = labels + b * Ln;

  // numerator: gold path score, lane-strided over t
  float part = 0.f;
  for (int t = lane; t < len; t += 64) {
    const int cur = tg[t];
    float v = (t == 0) ? (start_t[cur] + emb[cur])
                       : (trans[tg[t - 1] * Tn + cur] + emb[t * Tn + cur]);
    if (t == len - 1) v += end_t[cur];
    part += v;
  }
#pragma unroll
  for (int m = 1; m < 64; m <<= 1) part += __shfl_xor(part, m, 64);
  const float num = part;

  // denominator: v0 = start + em[0], then 8 matrix compositions
  const int j = (lane < Tn) ? lane : 0;
  float v = start_t[j] + emb[j];
#pragma unroll
  for (int c = 0; c < 8; ++c) {
    const float* Mc = M + (size_t)(b * 8 + c) * 81;
    float a[9];
#pragma unroll
    for (int i = 0; i < 9; ++i) a[i] = __shfl(v, i, 64) + Mc[i * 9 + j];
    float mx = a[0];
#pragma unroll
    for (int i = 1; i < 9; ++i) mx = fmaxf(mx, a[i]);
    float ssum = 0.f;
#pragma unroll
    for (int i = 0; i < 9; ++i) ssum += __expf(a[i] - mx);
    v = mx + __logf(ssum);
  }
  float fin = (lane < Tn) ? (v + end_t[j]) : -1.0e30f;
  float mx = fin;
#pragma unroll
  for (int m = 1; m < 64; m <<= 1) mx = fmaxf(mx, __shfl_xor(mx, m, 64));
  float se = __expf(fin - mx);
#pragma unroll
  for (int m = 1; m < 64; m <<= 1) se += __shfl_xor(se, m, 64);
  const float denom = mx + __logf(se);
  if (lane == 0) llh[b] = num - denom;
}

// ---------------------------------------------------------------------------
// K5: out = -mean(llh)
// ---------------------------------------------------------------------------
__global__ __launch_bounds__(64) void reduce_kernel(
    const float* __restrict__ llh, float* __restrict__ out)
{
  const int lane = threadIdx.x;
  float v = llh[lane] + llh[lane + 64];
#pragma unroll
  for (int m = 1; m < 64; m <<= 1) v += __shfl_xor(v, m, 64);
  if (lane == 0) out[0] = -v * (1.0f / Bn);
}

extern "C" void kernel_launch(void* const* d_in, const int* in_sizes, int n_in,
                              void* d_out, int out_size, void* d_ws, size_t ws_size,
                              hipStream_t stream) {
  const float* hidden  = (const float*)d_in[0];
  const float* W       = (const float*)d_in[1];
  const float* bias    = (const float*)d_in[2];
  const float* start_t = (const float*)d_in[3];
  const float* end_t   = (const float*)d_in[4];
  const float* trans   = (const float*)d_in[5];
  const int*   labels  = (const int*)d_in[6];
  const int*   lengths = (const int*)d_in[7];

  float* out  = (float*)d_out;
  float* wsf  = (float*)d_ws;
  float* part = wsf;                                // 4 * EMN
  float* em   = part + 4 * (size_t)EMN;             // EMN
  float* M    = em + (size_t)EMN;                   // 128*8*81 = 82944
  float* llh  = M + (size_t)Bn * 8 * 81;            // 128

  emis_mfma_kernel<<<NTILE, 256, 0, stream>>>(hidden, W, part);   // 2048 blocks
  combine_kernel<<<EMN / 256, 256, 0, stream>>>(part, bias, em);  // 1152 blocks
  crfA_kernel<<<Bn * 8 * 9, 64, 0, stream>>>(em, lengths, trans, M);
  crfB_kernel<<<Bn, 64, 0, stream>>>(em, labels, lengths, start_t, end_t, trans, M, llh);
  reduce_kernel<<<1, 64, 0, stream>>>(llh, out);
}

// Round 3
// 231.885 us; speedup vs baseline: 1.1227x; 1.0620x over previous
//
#include <hip/hip_runtime.h>
#include <math.h>

#define Bn 128
#define Ln 256
#define Hn 1024
#define Tn 9
#define NROWS (Bn * Ln)          // 32768
#define EMN   (NROWS * Tn)       // 294912
#define NC    16                 // CRF chunks per sequence
#define CW    16                 // chunk width (NC*CW = Ln)
#define NTASK (Bn * NC * 9)      // 18432 crfA tasks

typedef short short8 __attribute__((ext_vector_type(8)));
typedef float f32x4  __attribute__((ext_vector_type(4)));
typedef int   i32x4  __attribute__((ext_vector_type(4)));

__device__ __forceinline__ unsigned cvt_pk_bf16(float a, float b) {
  unsigned r;
  asm("v_cvt_pk_bf16_f32 %0, %1, %2" : "=v"(r) : "v"(a), "v"(b));
  return r;
}

__device__ __forceinline__ short8 pack_bf16x8(float4 lo, float4 hi) {
  i32x4 u;
  u[0] = cvt_pk_bf16(lo.x, lo.y);
  u[1] = cvt_pk_bf16(lo.z, lo.w);
  u[2] = cvt_pk_bf16(hi.x, hi.y);
  u[3] = cvt_pk_bf16(hi.z, hi.w);
  return __builtin_bit_cast(short8, u);
}

// ---------------------------------------------------------------------------
// K1: emissions GEMM via bf16 MFMA. Wave = one 16-row tile, full K=1024.
// A-frag: row = lane&15, k = m*32 + (lane>>4)*8 + j. B-frag: col = lane&15.
// C/D: col = lane&15 (tag), row = (lane>>4)*4 + reg.  ~100 VGPR, no spill.
// W re-read per wave from L2 (36 KB hot). Writes em = GEMM + bias directly.
// ---------------------------------------------------------------------------
#define LOADC(P, cc)                                         \
  P##A0 = *(const float4*)(Ap + (cc)*64);                    \
  P##A1 = *(const float4*)(Ap + (cc)*64 + 4);                \
  P##A2 = *(const float4*)(Ap + (cc)*64 + 32);               \
  P##A3 = *(const float4*)(Ap + (cc)*64 + 36);               \
  P##B0 = *(const float4*)(Bp + (cc)*64);                    \
  P##B1 = *(const float4*)(Bp + (cc)*64 + 4);                \
  P##B2 = *(const float4*)(Bp + (cc)*64 + 32);               \
  P##B3 = *(const float4*)(Bp + (cc)*64 + 36);

#define COMPC(P)                                             \
  acc = __builtin_amdgcn_mfma_f32_16x16x32_bf16(             \
      pack_bf16x8(P##A0, P##A1), pack_bf16x8(P##B0, P##B1), acc, 0, 0, 0); \
  acc = __builtin_amdgcn_mfma_f32_16x16x32_bf16(             \
      pack_bf16x8(P##A2, P##A3), pack_bf16x8(P##B2, P##B3), acc, 0, 0, 0);

__global__ __launch_bounds__(256, 2) void emis_kernel(
    const float* __restrict__ hidden, const float* __restrict__ W,
    const float* __restrict__ bias, float* __restrict__ em)
{
  const int lane = threadIdx.x & 63;
  const int tile = blockIdx.x * 4 + (threadIdx.x >> 6);   // 0..2047
  const int col  = lane & 15;
  const int g    = lane >> 4;
  const int wrow = (col < Tn) ? col : (Tn - 1);           // clamp B row (cols 9..15 unused)

  const float* Ap = hidden + ((size_t)tile * 16 + col) * Hn + g * 8;
  const float* Bp = W + (size_t)wrow * Hn + g * 8;

  float4 xA0, xA1, xA2, xA3, xB0, xB1, xB2, xB3;
  float4 yA0, yA1, yA2, yA3, yB0, yB1, yB2, yB3;
  f32x4 acc = {0.f, 0.f, 0.f, 0.f};

  LOADC(x, 0)
#pragma unroll
  for (int c = 0; c < 16; c += 2) {
    if (c + 1 < 16) { LOADC(y, c + 1) }
    COMPC(x)
    if (c + 2 < 16) { LOADC(x, c + 2) }
    COMPC(y)
  }

  if (col < Tn) {
    const float bcol = bias[col];
    const int rbase = tile * 16 + g * 4;
#pragma unroll
    for (int r = 0; r < 4; ++r)
      em[(size_t)(rbase + r) * Tn + col] = acc[r] + bcol;
  }
}

// ---------------------------------------------------------------------------
// K2: chunk transfer matrices, 7 chains per wave (groups of 9 lanes).
// Task (c-major) = c*1152 + b*9 + s0. Chunk c covers t in [max(1,16c), min(16c+16,len)).
// M[(b*NC+c)*81 + s0*9 + j] = log-semiring matrix. Empty chunk -> identity.
// ---------------------------------------------------------------------------
__global__ __launch_bounds__(64) void crfA_kernel(
    const float* __restrict__ em, const int* __restrict__ lengths,
    const float* __restrict__ trans, float* __restrict__ M)
{
  const int lane = threadIdx.x;
  const int g = lane / 9;                    // 0..7 (lane 63 -> g=7, idle)
  const int j = lane - g * 9;                // 0..8
  const int task0 = blockIdx.x * 7 + g;
  const bool act = (g < 7) && (task0 < NTASK);
  const int task = act ? task0 : 0;
  const int c  = task / (Bn * 9);
  const int rr = task - c * (Bn * 9);
  const int b  = rr / 9;
  const int s0 = rr - b * 9;
  int len = act ? lengths[b] : 0;

  int lo = c * CW; if (lo < 1) lo = 1;
  int hi = c * CW + CW; if (hi > len) hi = len;

  float trc[9];
#pragma unroll
  for (int i = 0; i < 9; ++i) trc[i] = trans[i * Tn + j];

  const float* emb = em + (size_t)b * Ln * Tn;
  float score = (j == s0) ? 0.f : -1.0e30f;
  const int base = g * 9;

  for (int t = lo; t < hi; ++t) {
    const float e = emb[t * Tn + j];         // independent of chain
    float a[9];
#pragma unroll
    for (int i = 0; i < 9; ++i) a[i] = __shfl(score, base + i, 64) + trc[i];
    float mx = a[0];
#pragma unroll
    for (int i = 1; i < 9; ++i) mx = fmaxf(mx, a[i]);
    float s = 0.f;
#pragma unroll
    for (int i = 0; i < 9; ++i) s += __expf(a[i] - mx);
    score = mx + __logf(s) + e;
  }

  if (act)
    M[(size_t)(b * NC + c) * 81 + s0 * 9 + j] = score;
}

// ---------------------------------------------------------------------------
// K3: per-batch numerator + compose NC chunk matrices -> llh[b]
// ---------------------------------------------------------------------------
__global__ __launch_bounds__(64) void crfB_kernel(
    const float* __restrict__ em, const int* __restrict__ labels,
    const int* __restrict__ lengths, const float* __restrict__ start_t,
    const float* __restrict__ end_t, const float* __restrict__ trans,
    const float* __restrict__ M, float* __restrict__ llh)
{
  const int b = blockIdx.x, lane = threadIdx.x;
  const int len = lengths[b];
  const float* emb = em + (size_t)b * Ln * Tn;
  const int* tg = labels + b * Ln;

  // numerator: gold path score, lane-strided over t
  float part = 0.f;
  for (int t = lane; t < len; t += 64) {
    const int cur = tg[t];
    float v = (t == 0) ? (start_t[cur] + emb[cur])
                       : (trans[tg[t - 1] * Tn + cur] + emb[t * Tn + cur]);
    if (t == len - 1) v += end_t[cur];
    part += v;
  }
#pragma unroll
  for (int m = 1; m < 64; m <<= 1) part += __shfl_xor(part, m, 64);
  const float num = part;

  // denominator: v0 = start + em[0], then NC matrix compositions
  const int j = (lane < Tn) ? lane : 0;
  float v = start_t[j] + emb[j];
#pragma unroll
  for (int c = 0; c < NC; ++c) {
    const float* Mc = M + (size_t)(b * NC + c) * 81;
    float a[9];
#pragma unroll
    for (int i = 0; i < 9; ++i) a[i] = __shfl(v, i, 64) + Mc[i * 9 + j];
    float mx = a[0];
#pragma unroll
    for (int i = 1; i < 9; ++i) mx = fmaxf(mx, a[i]);
    float s = 0.f;
#pragma unroll
    for (int i = 0; i < 9; ++i) s += __expf(a[i] - mx);
    v = mx + __logf(s);
  }
  float fin = (lane < Tn) ? (v + end_t[j]) : -1.0e30f;
  float mx = fin;
#pragma unroll
  for (int m = 1; m < 64; m <<= 1) mx = fmaxf(mx, __shfl_xor(mx, m, 64));
  float se = __expf(fin - mx);
#pragma unroll
  for (int m = 1; m < 64; m <<= 1) se += __shfl_xor(se, m, 64);
  const float denom = mx + __logf(se);
  if (lane == 0) llh[b] = num - denom;
}

// ---------------------------------------------------------------------------
// K4: out = -mean(llh)
// ---------------------------------------------------------------------------
__global__ __launch_bounds__(64) void reduce_kernel(
    const float* __restrict__ llh, float* __restrict__ out)
{
  const int lane = threadIdx.x;
  float v = llh[lane] + llh[lane + 64];
#pragma unroll
  for (int m = 1; m < 64; m <<= 1) v += __shfl_xor(v, m, 64);
  if (lane == 0) out[0] = -v * (1.0f / Bn);
}

extern "C" void kernel_launch(void* const* d_in, const int* in_sizes, int n_in,
                              void* d_out, int out_size, void* d_ws, size_t ws_size,
                              hipStream_t stream) {
  const float* hidden  = (const float*)d_in[0];
  const float* W       = (const float*)d_in[1];
  const float* bias    = (const float*)d_in[2];
  const float* start_t = (const float*)d_in[3];
  const float* end_t   = (const float*)d_in[4];
  const float* trans   = (const float*)d_in[5];
  const int*   labels  = (const int*)d_in[6];
  const int*   lengths = (const int*)d_in[7];

  float* out = (float*)d_out;
  float* wsf = (float*)d_ws;
  float* em  = wsf;                                 // EMN floats
  float* M   = em + (size_t)EMN;                    // Bn*NC*81
  float* llh = M + (size_t)Bn * NC * 81;            // 128

  emis_kernel<<<NROWS / 16 / 4, 256, 0, stream>>>(hidden, W, bias, em);   // 512 blocks
  crfA_kernel<<<(NTASK + 6) / 7, 64, 0, stream>>>(em, lengths, trans, M); // 2634 blocks
  crfB_kernel<<<Bn, 64, 0, stream>>>(em, labels, lengths, start_t, end_t, trans, M, llh);
  reduce_kernel<<<1, 64, 0, stream>>>(llh, out);
}

// Round 5
// 227.632 us; speedup vs baseline: 1.1437x; 1.0187x over previous
//
#include <hip/hip_runtime.h>
#include <math.h>

#define Bn 128
#define Ln 256
#define Hn 1024
#define Tn 9
#define NROWS (Bn * Ln)          // 32768
#define EMN   (NROWS * Tn)       // 294912
#define NC    16                 // CRF chunks per sequence
#define CW    16                 // chunk width (NC*CW = Ln)
#define NTASK (Bn * NC * 9)      // 18432 crfA tasks
#define INV_LN2 1.44269504088896341f
#define LN2_F   0.69314718055994531f

typedef short short8 __attribute__((ext_vector_type(8)));
typedef float f32x4  __attribute__((ext_vector_type(4)));
typedef int   i32x4  __attribute__((ext_vector_type(4)));

__device__ __forceinline__ float fexp2(float x) { return __builtin_amdgcn_exp2f(x); }
__device__ __forceinline__ float flog2(float x) { return __builtin_amdgcn_logf(x); }

__device__ __forceinline__ unsigned cvt_pk_bf16(float a, float b) {
  unsigned r;
  asm("v_cvt_pk_bf16_f32 %0, %1, %2" : "=v"(r) : "v"(a), "v"(b));
  return r;
}

__device__ __forceinline__ short8 pack_bf16x8(float4 lo, float4 hi) {
  i32x4 u;
  u[0] = cvt_pk_bf16(lo.x, lo.y);
  u[1] = cvt_pk_bf16(lo.z, lo.w);
  u[2] = cvt_pk_bf16(hi.x, hi.y);
  u[3] = cvt_pk_bf16(hi.z, hi.w);
  return __builtin_bit_cast(short8, u);
}

// ---------------------------------------------------------------------------
// K1: emissions GEMM via bf16 MFMA. Wave = one 16-row tile, full K=1024.
// 2-deep register double-buffer; 16KB/wave outstanding -> BW-saturated.
// A-frag: row = lane&15, k = c*64 + (lane>>4)*8 + j. C/D: col=lane&15,
// row=(lane>>4)*4+reg (m89-verified layout). ~150 VGPR under (256,2), no spill.
// ---------------------------------------------------------------------------
#define LOADC(P, cc)                                         \
  P##A0 = *(const float4*)(Ap + (cc)*64);                    \
  P##A1 = *(const float4*)(Ap + (cc)*64 + 4);                \
  P##A2 = *(const float4*)(Ap + (cc)*64 + 32);               \
  P##A3 = *(const float4*)(Ap + (cc)*64 + 36);               \
  P##B0 = *(const float4*)(Bp + (cc)*64);                    \
  P##B1 = *(const float4*)(Bp + (cc)*64 + 4);                \
  P##B2 = *(const float4*)(Bp + (cc)*64 + 32);               \
  P##B3 = *(const float4*)(Bp + (cc)*64 + 36);

#define COMPC(P)                                             \
  acc = __builtin_amdgcn_mfma_f32_16x16x32_bf16(             \
      pack_bf16x8(P##A0, P##A1), pack_bf16x8(P##B0, P##B1), acc, 0, 0, 0); \
  acc = __builtin_amdgcn_mfma_f32_16x16x32_bf16(             \
      pack_bf16x8(P##A2, P##A3), pack_bf16x8(P##B2, P##B3), acc, 0, 0, 0);

__global__ __launch_bounds__(256, 2) void emis_kernel(
    const float* __restrict__ hidden, const float* __restrict__ W,
    const float* __restrict__ bias, float* __restrict__ em)
{
  const int lane = threadIdx.x & 63;
  const int tile = blockIdx.x * 4 + (threadIdx.x >> 6);   // 0..2047
  const int col  = lane & 15;
  const int g    = lane >> 4;
  const int wrow = (col < Tn) ? col : (Tn - 1);           // clamp (cols 9..15 unused)

  const float* Ap = hidden + ((size_t)tile * 16 + col) * Hn + g * 8;
  const float* Bp = W + (size_t)wrow * Hn + g * 8;

  float4 xA0, xA1, xA2, xA3, xB0, xB1, xB2, xB3;
  float4 yA0, yA1, yA2, yA3, yB0, yB1, yB2, yB3;
  f32x4 acc = {0.f, 0.f, 0.f, 0.f};

  LOADC(x, 0)
#pragma unroll
  for (int c = 0; c < 16; c += 2) {
    if (c + 1 < 16) { LOADC(y, c + 1) }
    COMPC(x)
    if (c + 2 < 16) { LOADC(x, c + 2) }
    COMPC(y)
  }

  if (col < Tn) {
    const float bcol = bias[col];
    const int rbase = tile * 16 + g * 4;
#pragma unroll
    for (int r = 0; r < 4; ++r)
      em[(size_t)(rbase + r) * Tn + col] = acc[r] + bcol;
  }
}

// ---------------------------------------------------------------------------
// K2: chunk transfer matrices in LOG2 domain, 7 chains per wave.
// Task (c-major) = c*1152 + b*9 + s0; chunk c covers t in [max(1,16c),
// min(16c+16,len)); identity (0-diag) if empty. M stored in log2 units.
// Also zero-inits out[0] for crfB's atomic reduce (stream order).
// ---------------------------------------------------------------------------
__global__ __launch_bounds__(64) void crfA_kernel(
    const float* __restrict__ em, const int* __restrict__ lengths,
    const float* __restrict__ trans, float* __restrict__ M,
    float* __restrict__ out)
{
  if (blockIdx.x == 0 && threadIdx.x == 0) out[0] = 0.f;

  const int lane = threadIdx.x;
  const int g = lane / 9;                    // 0..7 (lane 63 idle)
  const int j = lane - g * 9;                // 0..8
  const int task0 = blockIdx.x * 7 + g;
  const bool act = (g < 7) && (task0 < NTASK);
  const int task = act ? task0 : 0;
  const int c  = task / (Bn * 9);
  const int rr = task - c * (Bn * 9);
  const int b  = rr / 9;
  const int s0 = rr - b * 9;
  int len = act ? lengths[b] : 0;

  int lo = c * CW; if (lo < 1) lo = 1;
  int hi = c * CW + CW; if (hi > len) hi = len;

  float trc2[9];
#pragma unroll
  for (int i = 0; i < 9; ++i) trc2[i] = trans[i * Tn + j] * INV_LN2;

  const float* emb = em + (size_t)b * Ln * Tn;
  float score = (j == s0) ? 0.f : -1.0e30f;  // log2 domain
  const int base = g * 9;

  for (int t = lo; t < hi; ++t) {
    const float e2 = emb[t * Tn + j] * INV_LN2;
    float a[9];
#pragma unroll
    for (int i = 0; i < 9; ++i) a[i] = __shfl(score, base + i, 64) + trc2[i];
    float mx = a[0];
#pragma unroll
    for (int i = 1; i < 9; ++i) mx = fmaxf(mx, a[i]);
    float s = 0.f;
#pragma unroll
    for (int i = 0; i < 9; ++i) s += fexp2(a[i] - mx);
    score = mx + flog2(s) + e2;
  }

  if (act)
    M[(size_t)(b * NC + c) * 81 + s0 * 9 + j] = score;
}

// ---------------------------------------------------------------------------
// K3: per-batch numerator + compose NC log2-domain chunk matrices,
// atomic-reduce straight into out[0] = -mean(llh).
// ---------------------------------------------------------------------------
__global__ __launch_bounds__(64) void crfB_kernel(
    const float* __restrict__ em, const int* __restrict__ labels,
    const int* __restrict__ lengths, const float* __restrict__ start_t,
    const float* __restrict__ end_t, const float* __restrict__ trans,
    const float* __restrict__ M, float* __restrict__ out)
{
  const int b = blockIdx.x, lane = threadIdx.x;
  const int len = lengths[b];
  const float* emb = em + (size_t)b * Ln * Tn;
  const int* tg = labels + b * Ln;

  // numerator: gold path score (natural log units), lane-strided over t
  float part = 0.f;
  for (int t = lane; t < len; t += 64) {
    const int cur = tg[t];
    float v = (t == 0) ? (start_t[cur] + emb[cur])
                       : (trans[tg[t - 1] * Tn + cur] + emb[t * Tn + cur]);
    if (t == len - 1) v += end_t[cur];
    part += v;
  }
#pragma unroll
  for (int m = 1; m < 64; m <<= 1) part += __shfl_xor(part, m, 64);
  const float num = part;

  // denominator in log2 domain: v2_0 = (start + em0)/ln2, then NC compositions
  const int j = (lane < Tn) ? lane : 0;
  float v2 = (start_t[j] + emb[j]) * INV_LN2;
#pragma unroll
  for (int c = 0; c < NC; ++c) {
    const float* Mc = M + (size_t)(b * NC + c) * 81;
    float a[9];
#pragma unroll
    for (int i = 0; i < 9; ++i) a[i] = __shfl(v2, i, 64) + Mc[i * 9 + j];
    float mx = a[0];
#pragma unroll
    for (int i = 1; i < 9; ++i) mx = fmaxf(mx, a[i]);
    float s = 0.f;
#pragma unroll
    for (int i = 0; i < 9; ++i) s += fexp2(a[i] - mx);
    v2 = mx + flog2(s);
  }
  float fin = (lane < Tn) ? (v2 + end_t[j] * INV_LN2) : -1.0e30f;
  float mx = fin;
#pragma unroll
  for (int m = 1; m < 64; m <<= 1) mx = fmaxf(mx, __shfl_xor(mx, m, 64));
  float se = fexp2(fin - mx);
#pragma unroll
  for (int m = 1; m < 64; m <<= 1) se += __shfl_xor(se, m, 64);
  const float denom = (mx + flog2(se)) * LN2_F;

  if (lane == 0) atomicAdd(out, (denom - num) * (1.0f / Bn));
}

extern "C" void kernel_launch(void* const* d_in, const int* in_sizes, int n_in,
                              void* d_out, int out_size, void* d_ws, size_t ws_size,
                              hipStream_t stream) {
  const float* hidden  = (const float*)d_in[0];
  const float* W       = (const float*)d_in[1];
  const float* bias    = (const float*)d_in[2];
  const float* start_t = (const float*)d_in[3];
  const float* end_t   = (const float*)d_in[4];
  const float* trans   = (const float*)d_in[5];
  const int*   labels  = (const int*)d_in[6];
  const int*   lengths = (const int*)d_in[7];

  float* out = (float*)d_out;
  float* wsf = (float*)d_ws;
  float* em  = wsf;                                 // EMN floats
  float* M   = em + (size_t)EMN;                    // Bn*NC*81 (log2 units)

  emis_kernel<<<NROWS / 16 / 4, 256, 0, stream>>>(hidden, W, bias, em);   // 512 blocks
  crfA_kernel<<<(NTASK + 6) / 7, 64, 0, stream>>>(em, lengths, trans, M, out);
  crfB_kernel<<<Bn, 64, 0, stream>>>(em, labels, lengths, start_t, end_t, trans, M, out);
}

// Round 6
// 214.360 us; speedup vs baseline: 1.2145x; 1.0619x over previous
//
#include <hip/hip_runtime.h>
#include <math.h>

#define Bn 128
#define Ln 256
#define Hn 1024
#define Tn 9
#define NROWS (Bn * Ln)          // 32768
#define EMN   (NROWS * Tn)       // 294912
#define NC    16                 // CRF chunks per sequence
#define CW    16                 // chunk width (NC*CW = Ln)
#define NTASK (Bn * NC * 9)      // 18432 crfA tasks
#define INV_LN2 1.44269504088896341f
#define LN2_F   0.69314718055994531f

typedef short short8 __attribute__((ext_vector_type(8)));
typedef float f32x4  __attribute__((ext_vector_type(4)));
typedef int   i32x4  __attribute__((ext_vector_type(4)));

__device__ __forceinline__ float fexp2(float x) { return __builtin_amdgcn_exp2f(x); }
__device__ __forceinline__ float flog2(float x) { return __builtin_amdgcn_logf(x); }

__device__ __forceinline__ unsigned cvt_pk_bf16(float a, float b) {
  unsigned r;
  asm("v_cvt_pk_bf16_f32 %0, %1, %2" : "=v"(r) : "v"(a), "v"(b));
  return r;
}

__device__ __forceinline__ short8 pack_bf16x8(float4 lo, float4 hi) {
  i32x4 u;
  u[0] = cvt_pk_bf16(lo.x, lo.y);
  u[1] = cvt_pk_bf16(lo.z, lo.w);
  u[2] = cvt_pk_bf16(hi.x, hi.y);
  u[3] = cvt_pk_bf16(hi.z, hi.w);
  return __builtin_bit_cast(short8, u);
}

// ---------------------------------------------------------------------------
// K1: emissions GEMM via bf16 MFMA. Wave = one 16-row tile, full K=1024.
// DEAD-TILE SKIP: emissions at t >= len[b] are never read downstream
// (mask semantics), so waves whose 16-row tile lies fully beyond len[b]
// exit before any vector loads — cuts streamed hidden bytes ~50%.
// A-frag: row = lane&15, k = c*64 + (lane>>4)*8 + j. C/D: col=lane&15,
// row=(lane>>4)*4+reg (m89-verified layout). ~150 VGPR under (256,2).
// ---------------------------------------------------------------------------
#define LOADC(P, cc)                                         \
  P##A0 = *(const float4*)(Ap + (cc)*64);                    \
  P##A1 = *(const float4*)(Ap + (cc)*64 + 4);                \
  P##A2 = *(const float4*)(Ap + (cc)*64 + 32);               \
  P##A3 = *(const float4*)(Ap + (cc)*64 + 36);               \
  P##B0 = *(const float4*)(Bp + (cc)*64);                    \
  P##B1 = *(const float4*)(Bp + (cc)*64 + 4);                \
  P##B2 = *(const float4*)(Bp + (cc)*64 + 32);               \
  P##B3 = *(const float4*)(Bp + (cc)*64 + 36);

#define COMPC(P)                                             \
  acc = __builtin_amdgcn_mfma_f32_16x16x32_bf16(             \
      pack_bf16x8(P##A0, P##A1), pack_bf16x8(P##B0, P##B1), acc, 0, 0, 0); \
  acc = __builtin_amdgcn_mfma_f32_16x16x32_bf16(             \
      pack_bf16x8(P##A2, P##A3), pack_bf16x8(P##B2, P##B3), acc, 0, 0, 0);

__global__ __launch_bounds__(256, 2) void emis_kernel(
    const float* __restrict__ hidden, const float* __restrict__ W,
    const float* __restrict__ bias, const int* __restrict__ lengths,
    float* __restrict__ em)
{
  const int lane = threadIdx.x & 63;
  const int tile = blockIdx.x * 4 + (threadIdx.x >> 6);   // 0..2047
  const int b    = tile >> 4;                             // batch
  const int ti   = tile & 15;                             // 16-row tile within batch

  if (ti * 16 >= lengths[b]) return;    // dead tile: emissions never read

  const int col  = lane & 15;
  const int g    = lane >> 4;
  const int wrow = (col < Tn) ? col : (Tn - 1);           // clamp (cols 9..15 unused)

  const float* Ap = hidden + ((size_t)tile * 16 + col) * Hn + g * 8;
  const float* Bp = W + (size_t)wrow * Hn + g * 8;

  float4 xA0, xA1, xA2, xA3, xB0, xB1, xB2, xB3;
  float4 yA0, yA1, yA2, yA3, yB0, yB1, yB2, yB3;
  f32x4 acc = {0.f, 0.f, 0.f, 0.f};

  LOADC(x, 0)
#pragma unroll
  for (int c = 0; c < 16; c += 2) {
    if (c + 1 < 16) { LOADC(y, c + 1) }
    COMPC(x)
    if (c + 2 < 16) { LOADC(x, c + 2) }
    COMPC(y)
  }

  if (col < Tn) {
    const float bcol = bias[col];
    const int rbase = tile * 16 + g * 4;
#pragma unroll
    for (int r = 0; r < 4; ++r)
      em[(size_t)(rbase + r) * Tn + col] = acc[r] + bcol;
  }
}

// ---------------------------------------------------------------------------
// K2: chunk transfer matrices in LOG2 domain, 7 chains per wave.
// Task (c-major) = c*1152 + b*9 + s0; chunk c covers t in [max(1,16c),
// min(16c+16,len)); identity (0-diag) if empty. M stored in log2 units.
// Also zero-inits out[0] for crfB's atomic reduce (stream order).
// ---------------------------------------------------------------------------
__global__ __launch_bounds__(64) void crfA_kernel(
    const float* __restrict__ em, const int* __restrict__ lengths,
    const float* __restrict__ trans, float* __restrict__ M,
    float* __restrict__ out)
{
  if (blockIdx.x == 0 && threadIdx.x == 0) out[0] = 0.f;

  const int lane = threadIdx.x;
  const int g = lane / 9;                    // 0..7 (lane 63 idle)
  const int j = lane - g * 9;                // 0..8
  const int task0 = blockIdx.x * 7 + g;
  const bool act = (g < 7) && (task0 < NTASK);
  const int task = act ? task0 : 0;
  const int c  = task / (Bn * 9);
  const int rr = task - c * (Bn * 9);
  const int b  = rr / 9;
  const int s0 = rr - b * 9;
  int len = act ? lengths[b] : 0;

  int lo = c * CW; if (lo < 1) lo = 1;
  int hi = c * CW + CW; if (hi > len) hi = len;

  float trc2[9];
#pragma unroll
  for (int i = 0; i < 9; ++i) trc2[i] = trans[i * Tn + j] * INV_LN2;

  const float* emb = em + (size_t)b * Ln * Tn;
  float score = (j == s0) ? 0.f : -1.0e30f;  // log2 domain
  const int base = g * 9;

  for (int t = lo; t < hi; ++t) {
    const float e2 = emb[t * Tn + j] * INV_LN2;
    float a[9];
#pragma unroll
    for (int i = 0; i < 9; ++i) a[i] = __shfl(score, base + i, 64) + trc2[i];
    float mx = a[0];
#pragma unroll
    for (int i = 1; i < 9; ++i) mx = fmaxf(mx, a[i]);
    float s = 0.f;
#pragma unroll
    for (int i = 0; i < 9; ++i) s += fexp2(a[i] - mx);
    score = mx + flog2(s) + e2;
  }

  if (act)
    M[(size_t)(b * NC + c) * 81 + s0 * 9 + j] = score;
}

// ---------------------------------------------------------------------------
// K3: per-batch numerator + compose NC log2-domain chunk matrices,
// atomic-reduce straight into out[0] = -mean(llh).
// ---------------------------------------------------------------------------
__global__ __launch_bounds__(64) void crfB_kernel(
    const float* __restrict__ em, const int* __restrict__ labels,
    const int* __restrict__ lengths, const float* __restrict__ start_t,
    const float* __restrict__ end_t, const float* __restrict__ trans,
    const float* __restrict__ M, float* __restrict__ out)
{
  const int b = blockIdx.x, lane = threadIdx.x;
  const int len = lengths[b];
  const float* emb = em + (size_t)b * Ln * Tn;
  const int* tg = labels + b * Ln;

  // numerator: gold path score (natural log units), lane-strided over t
  float part = 0.f;
  for (int t = lane; t < len; t += 64) {
    const int cur = tg[t];
    float v = (t == 0) ? (start_t[cur] + emb[cur])
                       : (trans[tg[t - 1] * Tn + cur] + emb[t * Tn + cur]);
    if (t == len - 1) v += end_t[cur];
    part += v;
  }
#pragma unroll
  for (int m = 1; m < 64; m <<= 1) part += __shfl_xor(part, m, 64);
  const float num = part;

  // denominator in log2 domain: v2_0 = (start + em0)/ln2, then NC compositions
  const int j = (lane < Tn) ? lane : 0;
  float v2 = (start_t[j] + emb[j]) * INV_LN2;
#pragma unroll
  for (int c = 0; c < NC; ++c) {
    const float* Mc = M + (size_t)(b * NC + c) * 81;
    float a[9];
#pragma unroll
    for (int i = 0; i < 9; ++i) a[i] = __shfl(v2, i, 64) + Mc[i * 9 + j];
    float mx = a[0];
#pragma unroll
    for (int i = 1; i < 9; ++i) mx = fmaxf(mx, a[i]);
    float s = 0.f;
#pragma unroll
    for (int i = 0; i < 9; ++i) s += fexp2(a[i] - mx);
    v2 = mx + flog2(s);
  }
  float fin = (lane < Tn) ? (v2 + end_t[j] * INV_LN2) : -1.0e30f;
  float mx = fin;
#pragma unroll
  for (int m = 1; m < 64; m <<= 1) mx = fmaxf(mx, __shfl_xor(mx, m, 64));
  float se = fexp2(fin - mx);
#pragma unroll
  for (int m = 1; m < 64; m <<= 1) se += __shfl_xor(se, m, 64);
  const float denom = (mx + flog2(se)) * LN2_F;

  if (lane == 0) atomicAdd(out, (denom - num) * (1.0f / Bn));
}

extern "C" void kernel_launch(void* const* d_in, const int* in_sizes, int n_in,
                              void* d_out, int out_size, void* d_ws, size_t ws_size,
                              hipStream_t stream) {
  const float* hidden  = (const float*)d_in[0];
  const float* W       = (const float*)d_in[1];
  const float* bias    = (const float*)d_in[2];
  const float* start_t = (const float*)d_in[3];
  const float* end_t   = (const float*)d_in[4];
  const float* trans   = (const float*)d_in[5];
  const int*   labels  = (const int*)d_in[6];
  const int*   lengths = (const int*)d_in[7];

  float* out = (float*)d_out;
  float* wsf = (float*)d_ws;
  float* em  = wsf;                                 // EMN floats
  float* M   = em + (size_t)EMN;                    // Bn*NC*81 (log2 units)

  emis_kernel<<<NROWS / 16 / 4, 256, 0, stream>>>(hidden, W, bias, lengths, em);
  crfA_kernel<<<(NTASK + 6) / 7, 64, 0, stream>>>(em, lengths, trans, M, out);
  crfB_kernel<<<Bn, 64, 0, stream>>>(em, labels, lengths, start_t, end_t, trans, M, out);
}